// Round 6
// baseline (666.909 us; speedup 1.0000x reference)
//
#include <hip/hip_runtime.h>
#include <hip/hip_bf16.h>
#include <stdint.h>

// Problem dims (fixed)
#define B_DIM 4096
#define DH    2048
#define K_DIM 4096   // D_IN + D_H (concat K)
#define N_DIM 8192   // 4 gates * DH (concat N), gate-interleaved layout
#define NT    128    // K tiles of 32

typedef __bf16  bf16x8 __attribute__((ext_vector_type(8)));
typedef float   f32x4  __attribute__((ext_vector_type(4)));

__device__ __forceinline__ unsigned short f2bf(float f) {
  unsigned int u = __float_as_uint(f);
  u += 0x7FFFu + ((u >> 16) & 1u);
  return (unsigned short)(u >> 16);
}

// ---------- kernel 1: cast+concat x,h -> A bf16 [4096][4096] ----------
__global__ void cast_cat_A(const float* __restrict__ x, const float* __restrict__ h,
                           unsigned short* __restrict__ Abuf) {
  int idx = blockIdx.x * 256 + threadIdx.x;
  const int half = B_DIM * (DH / 4);
  bool isx = (idx < half);
  int i2 = isx ? idx : idx - half;
  int b  = i2 >> 9;
  int c4 = i2 & 511;
  const float* src = (isx ? x : h) + (((size_t)b) << 11) + (c4 << 2);
  float4 v = *(const float4*)src;
  ushort4 o;
  o.x = f2bf(v.x); o.y = f2bf(v.y); o.z = f2bf(v.z); o.w = f2bf(v.w);
  int col = (isx ? 0 : DH) + (c4 << 2);
  *(ushort4*)(Abuf + (size_t)b * K_DIM + col) = o;
}

// ---------- kernel 2: transpose+cast weights -> Bt bf16 [8192][4096] ----------
//   n'(g, j) = (j>>5)*128 + ((j&16)<<2) + g*16 + (j&15)
// register-transpose 4x4 micro-tiles -> 4x ushort4 LDS writes per thread.
__global__ void transpose_cast_B(const float* __restrict__ Wi, const float* __restrict__ Ui,
                                 const float* __restrict__ Wf, const float* __restrict__ Uf,
                                 const float* __restrict__ Wo, const float* __restrict__ Uo,
                                 const float* __restrict__ Wz, const float* __restrict__ Uz,
                                 unsigned short* __restrict__ Bt) {
  __shared__ unsigned short lds[64 * 68];          // [n][k], stride 68 shorts
  const int k0 = blockIdx.x * 64;
  const int g  = blockIdx.y >> 5;
  const int j0 = (blockIdx.y & 31) * 64;
  const float* W = (g == 0) ? Wi : (g == 1) ? Wf : (g == 2) ? Wo : Wz;
  const float* U = (g == 0) ? Ui : (g == 1) ? Uf : (g == 2) ? Uo : Uz;
  const float* src = ((k0 < DH) ? (W + (size_t)k0 * DH)
                                : (U + (size_t)(k0 - DH) * DH)) + j0;
  const int t  = threadIdx.x;
  const int tk = t >> 4;                           // k-quad 0..15
  const int tj = t & 15;                           // j-quad 0..15
  float4 v[4];
  #pragma unroll
  for (int r = 0; r < 4; ++r)                      // 4 k-rows, one float4 of j each; coalesced
    v[r] = *(const float4*)(src + (size_t)(tk * 4 + r) * DH + tj * 4);
  #pragma unroll
  for (int jq = 0; jq < 4; ++jq) {                 // register 4x4 transpose -> vector LDS write
    int n = tj * 4 + jq;
    ushort4 w;
    w.x = f2bf(((const float*)&v[0])[jq]);
    w.y = f2bf(((const float*)&v[1])[jq]);
    w.z = f2bf(((const float*)&v[2])[jq]);
    w.w = f2bf(((const float*)&v[3])[jq]);
    *(ushort4*)(lds + n * 68 + tk * 4) = w;
  }
  __syncthreads();
  #pragma unroll
  for (int r = 0; r < 4; ++r) {                    // write [n'][k] coalesced along k
    int slot = r * 256 + t;
    int nn = slot >> 4;
    int c8 = slot & 15;
    int j  = j0 + nn;
    int np = ((j >> 5) << 7) + ((j & 16) << 2) + (g << 4) + (j & 15);
    *(ushort4*)(Bt + (size_t)np * K_DIM + k0 + (c8 << 2)) =
        *(const ushort4*)(lds + nn * 68 + (c8 << 2));
  }
}

// ---------- kernel 3: fused GEMM + gate epilogue (128x256, 4 waves, ring-3, 2 blocks/CU) ----------
// Restores inter-block TLP: 256 threads, 72 KiB LDS -> 2 blocks/CU. Independent
// block barriers let one block's MFMAs overlap the other's LDS-read storm
// (round-2's 1-block lockstep alternated the pipes: MfmaUtil 42%).
// Ring-3, BK=32: iter kt computes buf kt%3, stages tile kt+2 into buf (kt+2)%3
// (buf kt+1 untouched -> no region race; stage target was read in iter kt-1,
// whose end-of-tile barrier already retired those reads). 6 loads/tile/thread;
// end-of-tile vmcnt(6) retires exactly tile kt+1, keeps tile kt+2 in flight.
// LDS swizzle (2-bit, inside the 64-byte row): content[row][cb] = G[row][cb^(((row>>1)&3)<<4)],
// inverse-applied on the per-lane GLOBAL src (linear LDS dest) + same XOR on ds_read
// (measured 0 bank conflicts with identical pattern in rounds 2-4).
__global__ __launch_bounds__(256, 2) void gemm_gates(const unsigned short* __restrict__ A,
                                                     const unsigned short* __restrict__ Bt,
                                                     const float* __restrict__ bi, const float* __restrict__ bf,
                                                     const float* __restrict__ bo, const float* __restrict__ bz,
                                                     const float* __restrict__ cprev, const float* __restrict__ nprev,
                                                     float* __restrict__ out) {
  __shared__ alignas(16) unsigned short lds[36864];   // 72 KiB
  unsigned short* As = lds;            // [3][128][32] bf16 (buf stride 4096 ushorts)
  unsigned short* Bs = lds + 12288;    // [3][256][32] bf16 (buf stride 8192 ushorts)

  const int t    = threadIdx.x;
  const int w    = t >> 6;        // wave 0..3
  const int lane = t & 63;
  const int lm   = lane & 15;
  const int kg   = lane >> 4;     // 0..3
  const int wm2  = w >> 1;        // 0..1  (64-row half of the 128-row tile)
  const int wn2  = w & 1;         // 0..1  (128-col half of the 256-col tile)

  // bijective XCD swizzle: 1024 blocks, 1024 % 8 == 0; XCD groups share A-panels.
  const int flat = blockIdx.y * 32 + blockIdx.x;
  const int swzb = (flat & 7) * 128 + (flat >> 3);
  const int bx   = swzb & 31;     // n-tile 0..31 (256 cols each)
  const int by   = swzb >> 5;     // m-tile 0..31 (128 rows each)
  const int m0   = by * 128;
  const int n0   = bx * 256;

  // Staging: thread t handles A chunks {t, t+256} (rows t>>2, t>>2+64) and
  // B chunks {t, t+256, t+512, t+768} (rows t>>2 + 64q). All rows of one thread
  // differ by multiples of 64 -> same swizzle term; linear colbyte = (t&3)*16.
  const int rowA = t >> 2;                                   // 0..63
  const int kby  = ((t & 3) << 4) ^ (((t >> 3) & 3) << 4);   // inverse-swizzled src colbyte
  const unsigned short* pa0 = A  + (size_t)(m0 + rowA) * K_DIM + (kby >> 1);
  const unsigned short* pa1 = pa0 + (size_t)64  * K_DIM;
  const unsigned short* pb0 = Bt + (size_t)(n0 + rowA) * K_DIM + (kby >> 1);
  const unsigned short* pb1 = pb0 + (size_t)64  * K_DIM;
  const unsigned short* pb2 = pb0 + (size_t)128 * K_DIM;
  const unsigned short* pb3 = pb0 + (size_t)192 * K_DIM;
  const int ldsA0 = w * 512;            // wave-uniform LDS dests (ushort idx in buf)
  const int ldsA1 = 2048 + w * 512;
  const int ldsB0 = w * 512;
  const int ldsB1 = 2048 + w * 512;
  const int ldsB2 = 4096 + w * 512;
  const int ldsB3 = 6144 + w * 512;

  // Fragment ds_read byte offsets (within one buffer); row base multiple of 16
  // -> ((row>>1)&3) == ((lm>>1)&3).
  const int aoff = (wm2 * 64  + lm) * 64 + ((kg * 16) ^ (((lm >> 1) & 3) << 4));
  const int boff = (wn2 * 128 + lm) * 64 + ((kg * 16) ^ (((lm >> 1) & 3) << 4));
  const char* Asc = (const char*)As;
  const char* Bsc = (const char*)Bs;

  f32x4 acc[4][8] = {};

#define GLL(src, dst) __builtin_amdgcn_global_load_lds( \
    (const __attribute__((address_space(1))) unsigned int*)(src), \
    (__attribute__((address_space(3))) unsigned int*)(dst), 16, 0, 0)
#define STAGE(tile, buf) do {                                   \
    const size_t _k = (size_t)(tile) * 32;                      \
    GLL(pa0 + _k, As + (buf) * 4096 + ldsA0);                   \
    GLL(pa1 + _k, As + (buf) * 4096 + ldsA1);                   \
    GLL(pb0 + _k, Bs + (buf) * 8192 + ldsB0);                   \
    GLL(pb1 + _k, Bs + (buf) * 8192 + ldsB1);                   \
    GLL(pb2 + _k, Bs + (buf) * 8192 + ldsB2);                   \
    GLL(pb3 + _k, Bs + (buf) * 8192 + ldsB3);                   \
  } while (0)

  // Prologue: fill ring depth 2 (12 loads), require tile 0 resident (retire its 6).
  STAGE(0, 0); STAGE(1, 1);
  asm volatile("s_waitcnt vmcnt(6)" ::: "memory");
  __builtin_amdgcn_s_barrier();
  asm volatile("" ::: "memory");

  int cur = 0, stg = 2;
  for (int kt = 0; kt < NT; ++kt) {
    const char* ab = Asc + cur * 8192  + aoff;
    const char* bb = Bsc + cur * 16384 + boff;
    bf16x8 bv[8], avA, avB;

    #pragma unroll
    for (int ni = 0; ni < 8; ++ni) bv[ni] = *(const bf16x8*)(bb + ni * 1024);
    avA = *(const bf16x8*)(ab);
    if (kt + 2 < NT) STAGE(kt + 2, stg);

#define MM(avr, mi) do {                                                                  \
    __builtin_amdgcn_s_setprio(1);                                                        \
    _Pragma("unroll")                                                                     \
    for (int ni = 0; ni < 8; ++ni)                                                        \
      acc[mi][ni] = __builtin_amdgcn_mfma_f32_16x16x32_bf16(avr, bv[ni], acc[mi][ni], 0, 0, 0); \
    __builtin_amdgcn_s_setprio(0);                                                        \
  } while (0)

    avB = *(const bf16x8*)(ab + 1024);  MM(avA, 0);
    avA = *(const bf16x8*)(ab + 2048);  MM(avB, 1);
    avB = *(const bf16x8*)(ab + 3072);  MM(avA, 2);
    MM(avB, 3);
#undef MM

    // End-of-tile counted wait: retire tile kt+1 (read next iter); keep kt+2 in flight.
    if (kt + 2 < NT) asm volatile("s_waitcnt vmcnt(6)" ::: "memory");
    else             asm volatile("s_waitcnt vmcnt(0)" ::: "memory");
    __builtin_amdgcn_s_barrier();
    asm volatile("" ::: "memory");
    cur = (cur == 2) ? 0 : cur + 1;
    stg = (stg == 2) ? 0 : stg + 1;
  }

  // Epilogue: B-row r = n0 + wn2*128 + ni*16 + lm -> gate = ni&3, j-half = ni>>2,
  // j = (bx*2+wn2)*32 + (ni>>2)*16 + lm. C/D layout: col=lm, row=kg*4+r.
  const int jb = (bx * 2 + wn2) * 32;
  #pragma unroll
  for (int jh = 0; jh < 2; ++jh) {
    const int j = jb + jh * 16 + lm;
    const float vbi = bi[j], vbf = bf[j], vbo = bo[j], vbz = bz[j];
    #pragma unroll
    for (int mi = 0; mi < 4; ++mi) {
      const int mrow = m0 + wm2 * 64 + mi * 16 + kg * 4;
      #pragma unroll
      for (int r = 0; r < 4; ++r) {
        const size_t idx = (size_t)(mrow + r) * DH + j;
        float pi = acc[mi][jh * 4 + 0][r] + vbi;
        float pf = acc[mi][jh * 4 + 1][r] + vbf;
        float po = acc[mi][jh * 4 + 2][r] + vbo;
        float pz = acc[mi][jh * 4 + 3][r] + vbz;
        float iv = __expf(pi);
        float fv = __expf(pf);
        float ov = 1.0f / (1.0f + __expf(-po));
        float t2 = __expf(2.0f * pz);
        float zv = 1.0f - 2.0f / (t2 + 1.0f);
        float cv = fv * cprev[idx] + iv * zv;
        float nv = fv * nprev[idx] + iv;
        out[idx]            = ov * (cv / (nv + 1e-6f));  // h
        out[8388608 + idx]  = cv;                        // c
        out[16777216 + idx] = nv;                        // n
      }
    }
  }
#undef STAGE
#undef GLL
}

extern "C" void kernel_launch(void* const* d_in, const int* in_sizes, int n_in,
                              void* d_out, int out_size, void* d_ws, size_t ws_size,
                              hipStream_t stream) {
  const float* x      = (const float*)d_in[0];
  const float* h_prev = (const float*)d_in[1];
  const float* c_prev = (const float*)d_in[2];
  const float* n_prev = (const float*)d_in[3];
  const float* W_i = (const float*)d_in[4];  const float* b_i = (const float*)d_in[5];  const float* U_i = (const float*)d_in[6];
  const float* W_f = (const float*)d_in[7];  const float* b_f = (const float*)d_in[8];  const float* U_f = (const float*)d_in[9];
  const float* W_o = (const float*)d_in[10]; const float* b_o = (const float*)d_in[11]; const float* U_o = (const float*)d_in[12];
  const float* W_z = (const float*)d_in[13]; const float* b_z = (const float*)d_in[14]; const float* U_z = (const float*)d_in[15];
  float* out = (float*)d_out;

  char* ws = (char*)d_ws;
  unsigned short* Abuf = (unsigned short*)ws;                           // 33,554,432 B
  unsigned short* Bt   = (unsigned short*)(ws + 33554432);              // 67,108,864 B

  cast_cat_A<<<16384, 256, 0, stream>>>(x, h_prev, Abuf);
  transpose_cast_B<<<dim3(64, 128), 256, 0, stream>>>(W_i, U_i, W_f, U_f, W_o, U_o, W_z, U_z, Bt);
  gemm_gates<<<dim3(32, 32), 256, 0, stream>>>(Abuf, Bt, b_i, b_f, b_o, b_z, c_prev, n_prev, out);
}

// Round 7
// 551.009 us; speedup vs baseline: 1.2103x; 1.2103x over previous
//
#include <hip/hip_runtime.h>
#include <hip/hip_bf16.h>
#include <stdint.h>

// Problem dims (fixed)
#define B_DIM 4096
#define DH    2048
#define K_DIM 4096   // D_IN + D_H (concat K)
#define N_DIM 8192   // 4 gates * DH (concat N), gate-interleaved layout
#define NT    128    // K tiles of 32

typedef __bf16  bf16x8 __attribute__((ext_vector_type(8)));
typedef float   f32x4  __attribute__((ext_vector_type(4)));

__device__ __forceinline__ unsigned short f2bf(float f) {
  unsigned int u = __float_as_uint(f);
  u += 0x7FFFu + ((u >> 16) & 1u);
  return (unsigned short)(u >> 16);
}

// ---------- kernel 1: merged prep ----------
// blocks [0,8192): transpose+cast weights -> Bt bf16 [8192][4096],
//   n'(g, j) = (j>>5)*128 + ((j&16)<<2) + g*16 + (j&15)
//   (register-transpose 4x4 micro-tiles -> 4x ushort4 LDS writes; measured neutral
//    vs original in rounds 3-4, kept for fewer LDS ops)
// blocks [8192,9216): cast+concat x,h -> A bf16 [4096][4096], 16 float4/thread
//   (was 16384 one-float4-per-thread blocks; fatter blocks cut launch machinery)
__global__ __launch_bounds__(256) void prep(const float* __restrict__ x, const float* __restrict__ h,
                                            unsigned short* __restrict__ Abuf,
                                            const float* __restrict__ Wi, const float* __restrict__ Ui,
                                            const float* __restrict__ Wf, const float* __restrict__ Uf,
                                            const float* __restrict__ Wo, const float* __restrict__ Uo,
                                            const float* __restrict__ Wz, const float* __restrict__ Uz,
                                            unsigned short* __restrict__ Bt) {
  const int bid = blockIdx.x;
  const int t   = threadIdx.x;
  if (bid < 8192) {
    // ---- transpose part ----
    __shared__ unsigned short lds[64 * 68];        // [n][k], stride 68 shorts
    const int k0 = (bid & 63) * 64;
    const int gy = bid >> 6;
    const int g  = gy >> 5;
    const int j0 = (gy & 31) * 64;
    const float* W = (g == 0) ? Wi : (g == 1) ? Wf : (g == 2) ? Wo : Wz;
    const float* U = (g == 0) ? Ui : (g == 1) ? Uf : (g == 2) ? Uo : Uz;
    const float* src = ((k0 < DH) ? (W + (size_t)k0 * DH)
                                  : (U + (size_t)(k0 - DH) * DH)) + j0;
    const int tk = t >> 4;                         // k-quad 0..15
    const int tj = t & 15;                         // j-quad 0..15
    float4 v[4];
    #pragma unroll
    for (int r = 0; r < 4; ++r)                    // 4 k-rows, one float4 of j each; coalesced
      v[r] = *(const float4*)(src + (size_t)(tk * 4 + r) * DH + tj * 4);
    #pragma unroll
    for (int jq = 0; jq < 4; ++jq) {               // register 4x4 transpose -> vector LDS write
      int n = tj * 4 + jq;
      ushort4 wv;
      wv.x = f2bf(((const float*)&v[0])[jq]);
      wv.y = f2bf(((const float*)&v[1])[jq]);
      wv.z = f2bf(((const float*)&v[2])[jq]);
      wv.w = f2bf(((const float*)&v[3])[jq]);
      *(ushort4*)(lds + n * 68 + tk * 4) = wv;
    }
    __syncthreads();
    #pragma unroll
    for (int r = 0; r < 4; ++r) {                  // write [n'][k] coalesced along k
      int slot = r * 256 + t;
      int nn = slot >> 4;
      int c8 = slot & 15;
      int j  = j0 + nn;
      int np = ((j >> 5) << 7) + ((j & 16) << 2) + (g << 4) + (j & 15);
      *(ushort4*)(Bt + (size_t)np * K_DIM + k0 + (c8 << 2)) =
          *(const ushort4*)(lds + nn * 68 + (c8 << 2));
    }
  } else {
    // ---- cast+concat part ----
    const int cb   = bid - 8192;                   // 0..1023
    const int half = B_DIM * (DH / 4);             // 2,097,152 float4 units per source
    #pragma unroll
    for (int it = 0; it < 16; ++it) {
      int idx = cb * 4096 + it * 256 + t;          // 0 .. 4,194,303
      bool isx = (idx < half);
      int i2 = isx ? idx : idx - half;
      int b  = i2 >> 9;
      int c4 = i2 & 511;
      const float* src = (isx ? x : h) + (((size_t)b) << 11) + (c4 << 2);
      float4 v = *(const float4*)src;
      ushort4 o;
      o.x = f2bf(v.x); o.y = f2bf(v.y); o.z = f2bf(v.z); o.w = f2bf(v.w);
      int col = (isx ? 0 : DH) + (c4 << 2);
      *(ushort4*)(Abuf + (size_t)b * K_DIM + col) = o;
    }
  }
}

// ---------- kernel 2: fused GEMM + gate epilogue (256x256 tile, 4-deep ring) ----------
// ROUND-2 CHAMPION, verbatim (measured 284.7 us, MfmaUtil 42%, 0 bank conflicts).
// 8 waves (2M x 4N), BK=32. LDS ring: 4 bufs x (A[256][32] + B[256][32]) bf16 = 128 KiB.
// Iter kt: compute buf kt&3, stage tile kt+3 into buf (kt+3)&3 (bufs kt+1,kt+2 untouched).
// One raw s_barrier + counted vmcnt(8) per K-tile: 2 iters of global_load_lds stay in
// flight across the barrier (never drains to 0 except the 2-iter tail).
// LDS swizzle (2-bit, stays inside the 64-byte row):
//   content[row][cb] = Global[row][cb ^ (((row>>1)&3)<<4)]
// applied as inverse swizzle on the per-lane GLOBAL src (LDS dest stays linear)
// and the same XOR on the ds_read address.
// NOTE (rounds 3/4/6 post-mortems): extra per-phase barriers, wave-staggered cluster
// order, and 128x256/2-blocks-per-CU all REGRESSED vs this structure. Do not re-try.
__global__ __launch_bounds__(512, 2) void gemm_gates(const unsigned short* __restrict__ A,
                                                     const unsigned short* __restrict__ Bt,
                                                     const float* __restrict__ bi, const float* __restrict__ bf,
                                                     const float* __restrict__ bo, const float* __restrict__ bz,
                                                     const float* __restrict__ cprev, const float* __restrict__ nprev,
                                                     float* __restrict__ out) {
  __shared__ alignas(16) unsigned short lds[65536];   // 128 KiB
  unsigned short* As = lds;           // [4][256][32] bf16
  unsigned short* Bs = lds + 32768;   // [4][256][32] bf16

  const int t    = threadIdx.x;
  const int w    = t >> 6;        // wave 0..7
  const int lane = t & 63;
  const int lm   = lane & 15;
  const int kg   = lane >> 4;     // 0..3
  const int wm   = w >> 2;        // 0..1  (128-row half)
  const int wn   = w & 3;         // 0..3  (64-col quarter)

  // bijective XCD swizzle: 512 blocks, 512 % 8 == 0
  const int flat = blockIdx.y * 32 + blockIdx.x;
  const int swzb = (flat & 7) * 64 + (flat >> 3);
  const int bx   = swzb & 31;     // n-tile 0..31
  const int by   = swzb >> 5;     // m-tile 0..15
  const int m0   = by * 256;
  const int n0   = bx * 256;

  // Staging addresses (per thread 2 chunks for A + 2 for B per K-tile).
  const int r4 = lane >> 2, c4 = lane & 3;
  const int rowS0 = w * 32 + r4;
  const int rowS1 = rowS0 + 16;
  const int kby0 = (c4 * 16) ^ (((rowS0 >> 1) & 3) << 4);
  const int kby1 = (c4 * 16) ^ (((rowS1 >> 1) & 3) << 4);
  const unsigned short* pa0 = A  + (size_t)(m0 + rowS0) * K_DIM + (kby0 >> 1);
  const unsigned short* pa1 = A  + (size_t)(m0 + rowS1) * K_DIM + (kby1 >> 1);
  const unsigned short* pb0 = Bt + (size_t)(n0 + rowS0) * K_DIM + (kby0 >> 1);
  const unsigned short* pb1 = Bt + (size_t)(n0 + rowS1) * K_DIM + (kby1 >> 1);
  const int ldsQ0 = (w * 32) * 32;          // wave-uniform LDS dest (ushort idx)
  const int ldsQ1 = (w * 32 + 16) * 32;

  // Fragment ds_read byte offsets (within one 16 KiB buffer).
  const int aoff = (wm * 128 + lm) * 64 + ((kg * 16) ^ (((lm >> 1) & 3) << 4));
  const int boff = (wn * 64  + lm) * 64 + ((kg * 16) ^ (((lm >> 1) & 3) << 4));
  const char* Asc = (const char*)As;
  const char* Bsc = (const char*)Bs;

  f32x4 acc[8][4] = {};

#define STAGE(tile) do {                                                                              \
    const int _buf = (tile) & 3;                                                                      \
    const size_t _k = (size_t)(tile) * 32;                                                            \
    __builtin_amdgcn_global_load_lds((const __attribute__((address_space(1))) unsigned int*)(pa0 + _k), \
        (__attribute__((address_space(3))) unsigned int*)(As + _buf * 8192 + ldsQ0), 16, 0, 0);       \
    __builtin_amdgcn_global_load_lds((const __attribute__((address_space(1))) unsigned int*)(pa1 + _k), \
        (__attribute__((address_space(3))) unsigned int*)(As + _buf * 8192 + ldsQ1), 16, 0, 0);       \
    __builtin_amdgcn_global_load_lds((const __attribute__((address_space(1))) unsigned int*)(pb0 + _k), \
        (__attribute__((address_space(3))) unsigned int*)(Bs + _buf * 8192 + ldsQ0), 16, 0, 0);       \
    __builtin_amdgcn_global_load_lds((const __attribute__((address_space(1))) unsigned int*)(pb1 + _k), \
        (__attribute__((address_space(3))) unsigned int*)(Bs + _buf * 8192 + ldsQ1), 16, 0, 0);       \
  } while (0)

  // Prologue: fill ring depth 3 (12 loads), require tile 0 resident (retire oldest 4).
  STAGE(0); STAGE(1); STAGE(2);
  asm volatile("s_waitcnt vmcnt(8)" ::: "memory");
  __builtin_amdgcn_s_barrier();
  asm volatile("" ::: "memory");

  for (int kt = 0; kt < NT; ++kt) {
    const int cur = kt & 3;
    const char* ab = Asc + cur * 16384 + aoff;
    const char* bb = Bsc + cur * 16384 + boff;
    bf16x8 av[4], bv[4];

    #pragma unroll
    for (int ni = 0; ni < 4; ++ni) bv[ni] = *(const bf16x8*)(bb + ni * 1024);

    // phase 0: rows wm*128 + (0..3)*16
    #pragma unroll
    for (int i = 0; i < 4; ++i) av[i] = *(const bf16x8*)(ab + i * 1024);
    if (kt + 3 < NT) STAGE(kt + 3);
    __builtin_amdgcn_s_setprio(1);
    #pragma unroll
    for (int i = 0; i < 4; ++i)
      #pragma unroll
      for (int ni = 0; ni < 4; ++ni)
        acc[i][ni] = __builtin_amdgcn_mfma_f32_16x16x32_bf16(av[i], bv[ni], acc[i][ni], 0, 0, 0);
    __builtin_amdgcn_s_setprio(0);

    // phase 1: rows wm*128 + (4..7)*16
    #pragma unroll
    for (int i = 0; i < 4; ++i) av[i] = *(const bf16x8*)(ab + 4096 + i * 1024);
    __builtin_amdgcn_s_setprio(1);
    #pragma unroll
    for (int i = 0; i < 4; ++i)
      #pragma unroll
      for (int ni = 0; ni < 4; ++ni)
        acc[4 + i][ni] = __builtin_amdgcn_mfma_f32_16x16x32_bf16(av[i], bv[ni], acc[4 + i][ni], 0, 0, 0);
    __builtin_amdgcn_s_setprio(0);

    // End-of-tile counted wait: retire tile kt+1 (read next iter); keep 8 in flight.
    if (kt + 3 < NT)      asm volatile("s_waitcnt vmcnt(8)" ::: "memory");
    else if (kt + 2 < NT) asm volatile("s_waitcnt vmcnt(4)" ::: "memory");
    else                  asm volatile("s_waitcnt vmcnt(0)" ::: "memory");
    __builtin_amdgcn_s_barrier();
    asm volatile("" ::: "memory");
  }

  // Epilogue: ni == gate at column jj; C/D layout col=lm, row=kg*4+r.
  const int jj = (bx << 5) + ((wn >> 1) << 4) + lm;   // hmm see below
  // NOTE: round-2 mapping restored exactly: jj = bx*64 + (wn>>1)*32 + (wn&1)*16 + lm
  const int jj2 = bx * 64 + (wn >> 1) * 32 + (wn & 1) * 16 + lm;   // 0..2047
  (void)jj;
  const float vbi = bi[jj2], vbf = bf[jj2], vbo = bo[jj2], vbz = bz[jj2];
  #pragma unroll
  for (int mi = 0; mi < 8; ++mi) {
    const int mrow = m0 + wm * 128 + mi * 16 + kg * 4;
    #pragma unroll
    for (int r = 0; r < 4; ++r) {
      const size_t idx = (size_t)(mrow + r) * DH + jj2;
      float pi = acc[mi][0][r] + vbi;
      float pf = acc[mi][1][r] + vbf;
      float po = acc[mi][2][r] + vbo;
      float pz = acc[mi][3][r] + vbz;
      float iv = __expf(pi);
      float fv = __expf(pf);
      float ov = 1.0f / (1.0f + __expf(-po));
      float t2 = __expf(2.0f * pz);
      float zv = 1.0f - 2.0f / (t2 + 1.0f);
      float cv = fv * cprev[idx] + iv * zv;
      float nv = fv * nprev[idx] + iv;
      out[idx]            = ov * (cv / (nv + 1e-6f));  // h
      out[8388608 + idx]  = cv;                        // c
      out[16777216 + idx] = nv;                        // n
    }
  }
#undef STAGE
}

extern "C" void kernel_launch(void* const* d_in, const int* in_sizes, int n_in,
                              void* d_out, int out_size, void* d_ws, size_t ws_size,
                              hipStream_t stream) {
  const float* x      = (const float*)d_in[0];
  const float* h_prev = (const float*)d_in[1];
  const float* c_prev = (const float*)d_in[2];
  const float* n_prev = (const float*)d_in[3];
  const float* W_i = (const float*)d_in[4];  const float* b_i = (const float*)d_in[5];  const float* U_i = (const float*)d_in[6];
  const float* W_f = (const float*)d_in[7];  const float* b_f = (const float*)d_in[8];  const float* U_f = (const float*)d_in[9];
  const float* W_o = (const float*)d_in[10]; const float* b_o = (const float*)d_in[11]; const float* U_o = (const float*)d_in[12];
  const float* W_z = (const float*)d_in[13]; const float* b_z = (const float*)d_in[14]; const float* U_z = (const float*)d_in[15];
  float* out = (float*)d_out;

  char* ws = (char*)d_ws;
  unsigned short* Abuf = (unsigned short*)ws;                           // 33,554,432 B
  unsigned short* Bt   = (unsigned short*)(ws + 33554432);              // 67,108,864 B

  prep<<<9216, 256, 0, stream>>>(x, h_prev, Abuf,
                                 W_i, U_i, W_f, U_f, W_o, U_o, W_z, U_z, Bt);
  gemm_gates<<<dim3(32, 16), 512, 0, stream>>>(Abuf, Bt, b_i, b_f, b_o, b_z, c_prev, n_prev, out);
}